// Round 6
// baseline (222.274 us; speedup 1.0000x reference)
//
#include <hip/hip_runtime.h>
#include <hip/hip_bf16.h>

#define N_NODES 20000
#define N_EDGES 640000
#define HID 256
#define INDIM 128

// ---------- ws layout (bytes) ----------
#define WS_H_OFF    0u          // h bf16: 20000*256*2 = 10,240,000
#define WS_XBF_OFF  10240000u   // x bf16: 20000*128*2 = 5,120,000
#define WS_EW_OFF   15360000u   // emb_W bf16: 65,536
#define WS_MW_OFF   15425536u   // msg_W bf16: 131,072
#define WS_CS_OFF   15556608u   // colsum f32: 1024   (zeroed; contiguous with deg)
#define WS_DEG_OFF  15557632u   // deg: 80,000        (zeroed; doubles as fill cursor)
#define WS_ROW_OFF  15637632u   // rowstart: 80,004 (+124 pad)
#define WS_SRC_OFF  15717760u   // srcs: 2,560,000
#define WS_NEEDED   18277760u

#define X_ELEMS  (N_NODES * INDIM)          // 2,560,000
#define EW_ELEMS (HID * INDIM)              // 32,768
#define MW_ELEMS (HID * HID)                // 65,536
#define CONV_BLOCKS ((X_ELEMS + EW_ELEMS + MW_ELEMS) / 8 / 256)   // 1298 exact
#define ZERO_BYTES  (1024 + 80000)          // colsum + deg, contiguous
#define ZERO_F4     (ZERO_BYTES / 16)       // 5064 exact
#define ZERO_BLOCKS ((ZERO_F4 + 255) / 256) // 20

#define EMB_BLOCKS  ((N_NODES + 63) / 64)   // 313
#define CNT_BLOCKS  (N_EDGES / 256)         // 2500 exact

typedef __attribute__((ext_vector_type(8))) short bf16x8;
typedef __attribute__((ext_vector_type(4))) float f32x4;

__device__ inline unsigned short f2bf(float v) {
    union { float f; unsigned int u; } c; c.f = v;
    unsigned int lsb = (c.u >> 16) & 1u;
    c.u += 0x7fffu + lsb;                 // round-to-nearest-even
    return (unsigned short)(c.u >> 16);
}
__device__ inline float bf2f(unsigned short u) {
    union { float f; unsigned int u; } c; c.u = ((unsigned int)u) << 16;
    return c.f;
}

// ---------------------------------------------------------------------------
// Convert x, emb_W, msg_W to bf16; tail blocks zero colsum+deg (81 KB).
// ---------------------------------------------------------------------------
__global__ __launch_bounds__(256) void k_convert(const float* __restrict__ x,
                                                 const float* __restrict__ eW,
                                                 const float* __restrict__ mW,
                                                 unsigned short* __restrict__ xbf,
                                                 unsigned short* __restrict__ eWbf,
                                                 unsigned short* __restrict__ mWbf,
                                                 float4* __restrict__ zbase)
{
    if (blockIdx.x >= CONV_BLOCKS) {
        const int zi = (blockIdx.x - CONV_BLOCKS) * 256 + threadIdx.x;
        if (zi < ZERO_F4) zbase[zi] = make_float4(0.f, 0.f, 0.f, 0.f);
        return;
    }
    const int t = blockIdx.x * 256 + threadIdx.x;
    const int i8 = t * 8;
    const float* src;
    unsigned short* dst;
    int off;
    if (i8 < X_ELEMS)                 { src = x;  dst = xbf;  off = i8; }
    else if (i8 < X_ELEMS + EW_ELEMS) { src = eW; dst = eWbf; off = i8 - X_ELEMS; }
    else                              { src = mW; dst = mWbf; off = i8 - X_ELEMS - EW_ELEMS; }

    float4 a = *(const float4*)(src + off);
    float4 b = *(const float4*)(src + off + 4);
    unsigned short o[8] = { f2bf(a.x), f2bf(a.y), f2bf(a.z), f2bf(a.w),
                            f2bf(b.x), f2bf(b.y), f2bf(b.z), f2bf(b.w) };
    *(bf16x8*)(dst + off) = *(bf16x8*)o;
}

// ---------------------------------------------------------------------------
// MFMA embed (blocks < EMB_BLOCKS) + edge-degree count (blocks >= EMB_BLOCKS).
// deg was zeroed by k_convert (prior dispatch), so count here is race-free.
// ---------------------------------------------------------------------------
__global__ __launch_bounds__(256) void k_embed_count(const unsigned short* __restrict__ xbf,
                                                     const unsigned short* __restrict__ Wbf,
                                                     const float* __restrict__ b,
                                                     unsigned short* __restrict__ hbf,
                                                     const int* __restrict__ ei,
                                                     int* __restrict__ deg)
{
    if (blockIdx.x >= EMB_BLOCKS) {
        const int e = (blockIdx.x - EMB_BLOCKS) * 256 + threadIdx.x;
        if (e < N_EDGES) atomicAdd(&deg[ei[e]], 1);
        return;
    }

    const int tid  = threadIdx.x;
    const int wave = tid >> 6;
    const int lane = tid & 63;
    const int lr   = lane & 15;
    const int lq   = lane >> 4;
    const int n0   = blockIdx.x * 64;
    const int colbase = wave * 64;

    f32x4 acc[4][4] = {};

#pragma unroll
    for (int kk = 0; kk < INDIM; kk += 32) {
        bf16x8 a[4], bb[4];
#pragma unroll
        for (int g = 0; g < 4; ++g)
            a[g] = *(const bf16x8*)(xbf + (size_t)(n0 + g * 16 + lr) * INDIM + kk + lq * 8);
#pragma unroll
        for (int c = 0; c < 4; ++c)
            bb[c] = *(const bf16x8*)(Wbf + (size_t)(colbase + c * 16 + lr) * INDIM + kk + lq * 8);
#pragma unroll
        for (int g = 0; g < 4; ++g)
#pragma unroll
            for (int c = 0; c < 4; ++c)
                acc[g][c] = __builtin_amdgcn_mfma_f32_16x16x32_bf16(a[g], bb[c], acc[g][c], 0, 0, 0);
    }

#pragma unroll
    for (int c = 0; c < 4; ++c) {
        const int j = colbase + c * 16 + lr;
        const float bias = b[j];
#pragma unroll
        for (int g = 0; g < 4; ++g) {
            const int nbase = n0 + g * 16 + lq * 4;
#pragma unroll
            for (int r = 0; r < 4; ++r) {
                const int n = nbase + r;
                if (n < N_NODES) {
                    float v = acc[g][c][r] + bias;
                    v = v > 0.f ? v : 0.f;
                    hbf[(size_t)n * HID + j] = f2bf(v);
                }
            }
        }
    }
}

// ---------------------------------------------------------------------------
// Exclusive prefix sum of deg -> rowstart (single block).
// ---------------------------------------------------------------------------
__global__ __launch_bounds__(1024) void k_scan(const int* __restrict__ deg,
                                               int* __restrict__ rowstart)
{
    __shared__ int sums[1024];
    const int t = threadIdx.x;
    const int per = 20;                     // 1024*20 = 20480 >= 20000
    const int base = t * per;

    int local[per];
    int s = 0;
#pragma unroll
    for (int i = 0; i < per; ++i) {
        int idx = base + i;
        int v = (idx < N_NODES) ? deg[idx] : 0;
        local[i] = s;
        s += v;
    }
    sums[t] = s;
    __syncthreads();

    for (int off = 1; off < 1024; off <<= 1) {
        int v = 0;
        if (t >= off) v = sums[t - off];
        __syncthreads();
        if (t >= off) sums[t] += v;
        __syncthreads();
    }

    const int pre = (t == 0) ? 0 : sums[t - 1];
#pragma unroll
    for (int i = 0; i < per; ++i) {
        int idx = base + i;
        if (idx < N_NODES) rowstart[idx] = pre + local[i];
    }
    if (t == 1023) rowstart[N_NODES] = sums[1023];
}

// deg[dst] still holds the count; consume it as a countdown cursor
// (self-zeroes, but deg is re-zeroed by k_convert each call anyway).
__global__ __launch_bounds__(256) void k_fill(const int* __restrict__ ei,
                                              const int* __restrict__ rowstart,
                                              int* __restrict__ deg,
                                              int* __restrict__ srcs)
{
    const int e = blockIdx.x * 256 + threadIdx.x;
    if (e >= N_EDGES) return;
    const int dst = ei[e];
    const int src = ei[N_EDGES + e];
    const int pos = rowstart[dst] + atomicSub(&deg[dst], 1) - 1;
    srcs[pos] = src;
}

// ---------------------------------------------------------------------------
// Fused gather + msg layer: per 64-node tile, gather agg rows into a
// swizzled LDS tile (bf16), then h2 = relu(agg @ msg_W.T + msg_b) via MFMA,
// column-summed into colsum. agg never touches global memory.
// LDS swizzle: byte ^= (row&7)<<4 — conflict-free for 8B stores (lane-
// consecutive within a row) and for the b128 A-frag reads (16 lanes read
// 16 rows at one col-slot -> 8 distinct 16B slots x2 = 2-way, free).
// ---------------------------------------------------------------------------
__global__ __launch_bounds__(256) void k_gmsg(const int* __restrict__ rowstart,
                                              const int* __restrict__ srcs,
                                              const unsigned short* __restrict__ hbf,
                                              const unsigned short* __restrict__ Wbf,
                                              const float* __restrict__ b,
                                              float* __restrict__ colsum)
{
    __shared__ unsigned short lds[64 * HID];   // 32 KB
    const int tid  = threadIdx.x;
    const int wave = tid >> 6;
    const int lane = tid & 63;
    const int n0   = blockIdx.x * 64;

    // ---- phase 1: each wave gathers 16 nodes (lane owns 4 columns) ----
    const ushort4* h4 = (const ushort4*)hbf;
    for (int i = 0; i < 16; ++i) {
        const int r    = wave * 16 + i;          // row in tile
        const int node = n0 + r;
        float4 acc = make_float4(0.f, 0.f, 0.f, 0.f);
        if (node < N_NODES) {
            const int s0 = rowstart[node];
            const int s1 = rowstart[node + 1];
            int e = s0;
            for (; e + 3 < s1; e += 4) {
                int sA = srcs[e], sB = srcs[e + 1], sC = srcs[e + 2], sD = srcs[e + 3];
                ushort4 a = h4[(size_t)sA * 64 + lane];
                ushort4 bv = h4[(size_t)sB * 64 + lane];
                ushort4 c = h4[(size_t)sC * 64 + lane];
                ushort4 d = h4[(size_t)sD * 64 + lane];
                acc.x += (bf2f(a.x) + bf2f(bv.x)) + (bf2f(c.x) + bf2f(d.x));
                acc.y += (bf2f(a.y) + bf2f(bv.y)) + (bf2f(c.y) + bf2f(d.y));
                acc.z += (bf2f(a.z) + bf2f(bv.z)) + (bf2f(c.z) + bf2f(d.z));
                acc.w += (bf2f(a.w) + bf2f(bv.w)) + (bf2f(c.w) + bf2f(d.w));
            }
            for (; e < s1; ++e) {
                ushort4 a = h4[(size_t)srcs[e] * 64 + lane];
                acc.x += bf2f(a.x);
                acc.y += bf2f(a.y);
                acc.z += bf2f(a.z);
                acc.w += bf2f(a.w);
            }
        }
        ushort4 o;
        o.x = f2bf(acc.x); o.y = f2bf(acc.y); o.z = f2bf(acc.z); o.w = f2bf(acc.w);
        const unsigned byteoff = (unsigned)r * 512u + (((unsigned)lane * 8u) ^ (((unsigned)r & 7u) << 4));
        *(ushort4*)((char*)lds + byteoff) = o;
    }
    __syncthreads();

    // ---- phase 2: MFMA from LDS (A) and global W (B) ----
    const int lr = lane & 15;
    const int lq = lane >> 4;
    const int colbase = wave * 64;

    f32x4 acc[4][4] = {};

#pragma unroll
    for (int kk = 0; kk < HID; kk += 32) {
        bf16x8 a[4], bb[4];
#pragma unroll
        for (int g = 0; g < 4; ++g) {
            const int r = g * 16 + lr;
            const unsigned byteoff = (unsigned)r * 512u
                + (((unsigned)(kk * 2 + lq * 16)) ^ (((unsigned)r & 7u) << 4));
            a[g] = *(const bf16x8*)((const char*)lds + byteoff);
        }
#pragma unroll
        for (int c = 0; c < 4; ++c)
            bb[c] = *(const bf16x8*)(Wbf + (size_t)(colbase + c * 16 + lr) * HID + kk + lq * 8);
#pragma unroll
        for (int g = 0; g < 4; ++g)
#pragma unroll
            for (int c = 0; c < 4; ++c)
                acc[g][c] = __builtin_amdgcn_mfma_f32_16x16x32_bf16(a[g], bb[c], acc[g][c], 0, 0, 0);
    }

#pragma unroll
    for (int c = 0; c < 4; ++c) {
        const int j = colbase + c * 16 + lr;
        const float bias = b[j];
        float part = 0.f;
#pragma unroll
        for (int g = 0; g < 4; ++g) {
            if (n0 + g * 16 < N_NODES) {      // 20000 % 16 == 0: exact cut
#pragma unroll
                for (int r = 0; r < 4; ++r) {
                    float v = acc[g][c][r] + bias;
                    part += v > 0.f ? v : 0.f;
                }
            }
        }
        part += __shfl_xor(part, 16);
        part += __shfl_xor(part, 32);
        if (lane < 16) unsafeAtomicAdd(&colsum[j], part);
    }
}

// ---------------------------------------------------------------------------
// Output matvecs from hmean = colsum / N.
// ---------------------------------------------------------------------------
__global__ __launch_bounds__(256) void k_out(const float* __restrict__ colsum,
                                             const float* __restrict__ W0,
                                             const float* __restrict__ b0,
                                             const float* __restrict__ W1,
                                             const float* __restrict__ b1,
                                             float* __restrict__ out)
{
    __shared__ float hm[HID];
    const int tid = threadIdx.x;
    hm[tid] = colsum[tid] * (1.0f / (float)N_NODES);
    __syncthreads();

    const int o = blockIdx.x * 256 + tid;
    const float* Wr;
    float bias;
    if (o < 8192) { Wr = W0 + (size_t)o * HID; bias = b0[o]; }
    else          { int o1 = o - 8192; Wr = W1 + (size_t)o1 * HID; bias = b1[o1]; }

    float s = bias;
    const float4* w4 = (const float4*)Wr;
    const float4* h4 = (const float4*)hm;
#pragma unroll 8
    for (int q = 0; q < 64; ++q) {
        float4 wv = w4[q];
        float4 hv = h4[q];
        s += wv.x * hv.x + wv.y * hv.y + wv.z * hv.z + wv.w * hv.w;
    }
    out[o] = s;
}

// ---------------------------------------------------------------------------
extern "C" void kernel_launch(void* const* d_in, const int* in_sizes, int n_in,
                              void* d_out, int out_size, void* d_ws, size_t ws_size,
                              hipStream_t stream)
{
    const float* x     = (const float*)d_in[0];
    const int*   ei    = (const int*)d_in[1];
    const float* emb_W = (const float*)d_in[2];
    const float* emb_b = (const float*)d_in[3];
    const float* msg_W = (const float*)d_in[4];
    const float* msg_b = (const float*)d_in[5];
    const float* W0    = (const float*)d_in[6];
    const float* b0    = (const float*)d_in[7];
    const float* W1    = (const float*)d_in[8];
    const float* b1    = (const float*)d_in[9];
    float* out = (float*)d_out;

    char* ws = (char*)d_ws;
    unsigned short* hbf   = (unsigned short*)(ws + WS_H_OFF);
    unsigned short* xbf   = (unsigned short*)(ws + WS_XBF_OFF);
    unsigned short* eWbf  = (unsigned short*)(ws + WS_EW_OFF);
    unsigned short* mWbf  = (unsigned short*)(ws + WS_MW_OFF);
    float* colsum = (float*)(ws + WS_CS_OFF);
    int* deg      = (int*)(ws + WS_DEG_OFF);
    int* rowstart = (int*)(ws + WS_ROW_OFF);
    int* srcs     = (int*)(ws + WS_SRC_OFF);

    // 1. convert to bf16 + zero colsum/deg
    k_convert<<<CONV_BLOCKS + ZERO_BLOCKS, 256, 0, stream>>>(
        x, emb_W, msg_W, xbf, eWbf, mWbf, (float4*)(ws + WS_CS_OFF));

    // 2. embed (MFMA) + degree count
    k_embed_count<<<EMB_BLOCKS + CNT_BLOCKS, 256, 0, stream>>>(
        xbf, eWbf, emb_b, hbf, ei, deg);

    // 3-4. CSR scan + fill
    k_scan<<<1, 1024, 0, stream>>>(deg, rowstart);
    k_fill<<<CNT_BLOCKS, 256, 0, stream>>>(ei, rowstart, deg, srcs);

    // 5. fused gather + msg layer + column-sum
    k_gmsg<<<EMB_BLOCKS, 256, 0, stream>>>(rowstart, srcs, hbf, mWbf, msg_b, colsum);

    // 6. output matvecs
    k_out<<<(8192 + 2048) / 256, 256, 0, stream>>>(colsum, W0, b0, W1, b1, out);
}

// Round 7
// 174.624 us; speedup vs baseline: 1.2729x; 1.2729x over previous
//
#include <hip/hip_runtime.h>
#include <hip/hip_bf16.h>

#define N_NODES 20000
#define N_EDGES 640000
#define HID 256
#define INDIM 128

// ---------- ws layout (bytes) ----------
#define WS_H_OFF    0u          // h fp8: 20000*256 = 5,120,000
#define WS_AGG_OFF  5120000u    // agg bf16: 20000*256*2 = 10,240,000
#define WS_XBF_OFF  15360000u   // x bf16: 20000*128*2 = 5,120,000
#define WS_EW_OFF   20480000u   // emb_W bf16: 65,536
#define WS_MW_OFF   20545536u   // msg_W bf16: 131,072
#define WS_CS_OFF   20676608u   // colsum f32: 1024   (zeroed; contiguous with deg)
#define WS_DEG_OFF  20677632u   // deg: 80,000        (zeroed; doubles as fill cursor)
#define WS_ROW_OFF  20757632u   // rowstart: 80,004 (+124 pad)
#define WS_SRC_OFF  20837760u   // srcs: 2,560,000
#define WS_NEEDED   23397760u

#define X_ELEMS  (N_NODES * INDIM)          // 2,560,000
#define EW_ELEMS (HID * INDIM)              // 32,768
#define MW_ELEMS (HID * HID)                // 65,536
#define CONV_BLOCKS ((X_ELEMS + EW_ELEMS + MW_ELEMS) / 8 / 256)   // 1298 exact
#define ZERO_BYTES  (1024 + 80000)          // colsum + deg, contiguous
#define ZERO_F4     (ZERO_BYTES / 16)       // 5064 exact
#define ZERO_BLOCKS ((ZERO_F4 + 255) / 256) // 20

#define EMB_BLOCKS  ((N_NODES + 63) / 64)   // 313
#define CNT_BLOCKS  (N_EDGES / 256)         // 2500 exact

typedef __attribute__((ext_vector_type(8))) short bf16x8;
typedef __attribute__((ext_vector_type(4))) float f32x4;

__device__ inline unsigned short f2bf(float v) {
    union { float f; unsigned int u; } c; c.f = v;
    unsigned int lsb = (c.u >> 16) & 1u;
    c.u += 0x7fffu + lsb;                 // round-to-nearest-even
    return (unsigned short)(c.u >> 16);
}
__device__ inline float bf2f(unsigned short u) {
    union { float f; unsigned int u; } c; c.u = ((unsigned int)u) << 16;
    return c.f;
}

// ---- fp8 e4m3fn (OCP), nonnegative inputs only (h is post-relu) ----------
// encode: RTNE, exact for 0 and denormals; h <= ~4 so no sat needed.
__device__ inline unsigned char f2fp8(float v) {
    union { float f; unsigned int u; } c; c.f = v;
    if (v == 0.f) return 0;
    int e = (int)((c.u >> 23) & 0xff) - 127;
    if (e >= -6) {
        unsigned int mant = c.u & 0x7fffffu;
        unsigned int base = ((unsigned int)(e + 7) << 3) | (mant >> 20);
        unsigned int rem  = mant & 0xfffffu;
        base += (rem > 0x80000u) || (rem == 0x80000u && (base & 1u));
        return (unsigned char)base;
    } else {
        // denormal: m = round(v * 512), m in [0,8] (m==8 -> 0x08, exact)
        return (unsigned char)__builtin_rintf(v * 512.0f);
    }
}
// decode: 0x00-0x7f (sign always 0). norm = 2^(e-7)*(1+m/8); den = m*2^-9.
__device__ inline float fp8tof(unsigned int b) {
    union { unsigned int u; float f; } c;
    c.u = ((b & 0x7fu) << 20) + 0x3C000000u;
    float den = (float)(b & 7u) * 0.001953125f;
    return (b & 0x78u) ? c.f : den;
}

// ---------------------------------------------------------------------------
// Convert x, emb_W, msg_W to bf16; tail blocks zero colsum+deg (81 KB).
// ---------------------------------------------------------------------------
__global__ __launch_bounds__(256) void k_convert(const float* __restrict__ x,
                                                 const float* __restrict__ eW,
                                                 const float* __restrict__ mW,
                                                 unsigned short* __restrict__ xbf,
                                                 unsigned short* __restrict__ eWbf,
                                                 unsigned short* __restrict__ mWbf,
                                                 float4* __restrict__ zbase)
{
    if (blockIdx.x >= CONV_BLOCKS) {
        const int zi = (blockIdx.x - CONV_BLOCKS) * 256 + threadIdx.x;
        if (zi < ZERO_F4) zbase[zi] = make_float4(0.f, 0.f, 0.f, 0.f);
        return;
    }
    const int t = blockIdx.x * 256 + threadIdx.x;
    const int i8 = t * 8;
    const float* src;
    unsigned short* dst;
    int off;
    if (i8 < X_ELEMS)                 { src = x;  dst = xbf;  off = i8; }
    else if (i8 < X_ELEMS + EW_ELEMS) { src = eW; dst = eWbf; off = i8 - X_ELEMS; }
    else                              { src = mW; dst = mWbf; off = i8 - X_ELEMS - EW_ELEMS; }

    float4 a = *(const float4*)(src + off);
    float4 b = *(const float4*)(src + off + 4);
    unsigned short o[8] = { f2bf(a.x), f2bf(a.y), f2bf(a.z), f2bf(a.w),
                            f2bf(b.x), f2bf(b.y), f2bf(b.z), f2bf(b.w) };
    *(bf16x8*)(dst + off) = *(bf16x8*)o;
}

// ---------------------------------------------------------------------------
// MFMA embed (blocks < EMB_BLOCKS) + edge-degree count (blocks >= EMB_BLOCKS).
// h stored as fp8 e4m3 (5.1 MB -> mostly per-XCD-L2-resident for gather).
// ---------------------------------------------------------------------------
__global__ __launch_bounds__(256) void k_embed_count(const unsigned short* __restrict__ xbf,
                                                     const unsigned short* __restrict__ Wbf,
                                                     const float* __restrict__ b,
                                                     unsigned char* __restrict__ h8,
                                                     const int* __restrict__ ei,
                                                     int* __restrict__ deg)
{
    if (blockIdx.x >= EMB_BLOCKS) {
        const int e = (blockIdx.x - EMB_BLOCKS) * 256 + threadIdx.x;
        if (e < N_EDGES) atomicAdd(&deg[ei[e]], 1);
        return;
    }

    const int tid  = threadIdx.x;
    const int wave = tid >> 6;
    const int lane = tid & 63;
    const int lr   = lane & 15;
    const int lq   = lane >> 4;
    const int n0   = blockIdx.x * 64;
    const int colbase = wave * 64;

    f32x4 acc[4][4] = {};

#pragma unroll
    for (int kk = 0; kk < INDIM; kk += 32) {
        bf16x8 a[4], bb[4];
#pragma unroll
        for (int g = 0; g < 4; ++g)
            a[g] = *(const bf16x8*)(xbf + (size_t)(n0 + g * 16 + lr) * INDIM + kk + lq * 8);
#pragma unroll
        for (int c = 0; c < 4; ++c)
            bb[c] = *(const bf16x8*)(Wbf + (size_t)(colbase + c * 16 + lr) * INDIM + kk + lq * 8);
#pragma unroll
        for (int g = 0; g < 4; ++g)
#pragma unroll
            for (int c = 0; c < 4; ++c)
                acc[g][c] = __builtin_amdgcn_mfma_f32_16x16x32_bf16(a[g], bb[c], acc[g][c], 0, 0, 0);
    }

#pragma unroll
    for (int c = 0; c < 4; ++c) {
        const int j = colbase + c * 16 + lr;
        const float bias = b[j];
#pragma unroll
        for (int g = 0; g < 4; ++g) {
            const int nbase = n0 + g * 16 + lq * 4;
#pragma unroll
            for (int r = 0; r < 4; ++r) {
                const int n = nbase + r;
                if (n < N_NODES) {
                    float v = acc[g][c][r] + bias;
                    v = v > 0.f ? v : 0.f;
                    h8[(size_t)n * HID + j] = f2fp8(v);
                }
            }
        }
    }
}

// ---------------------------------------------------------------------------
// Exclusive prefix sum of deg -> rowstart (single block).
// ---------------------------------------------------------------------------
__global__ __launch_bounds__(1024) void k_scan(const int* __restrict__ deg,
                                               int* __restrict__ rowstart)
{
    __shared__ int sums[1024];
    const int t = threadIdx.x;
    const int per = 20;                     // 1024*20 = 20480 >= 20000
    const int base = t * per;

    int local[per];
    int s = 0;
#pragma unroll
    for (int i = 0; i < per; ++i) {
        int idx = base + i;
        int v = (idx < N_NODES) ? deg[idx] : 0;
        local[i] = s;
        s += v;
    }
    sums[t] = s;
    __syncthreads();

    for (int off = 1; off < 1024; off <<= 1) {
        int v = 0;
        if (t >= off) v = sums[t - off];
        __syncthreads();
        if (t >= off) sums[t] += v;
        __syncthreads();
    }

    const int pre = (t == 0) ? 0 : sums[t - 1];
#pragma unroll
    for (int i = 0; i < per; ++i) {
        int idx = base + i;
        if (idx < N_NODES) rowstart[idx] = pre + local[i];
    }
    if (t == 1023) rowstart[N_NODES] = sums[1023];
}

// deg[dst] still holds the count; consume it as a countdown cursor.
__global__ __launch_bounds__(256) void k_fill(const int* __restrict__ ei,
                                              const int* __restrict__ rowstart,
                                              int* __restrict__ deg,
                                              int* __restrict__ srcs)
{
    const int e = blockIdx.x * 256 + threadIdx.x;
    if (e >= N_EDGES) return;
    const int dst = ei[e];
    const int src = ei[N_EDGES + e];
    const int pos = rowstart[dst] + atomicSub(&deg[dst], 1) - 1;
    srcs[pos] = src;
}

// ---------------------------------------------------------------------------
// Gather: one wave per dst node (20000 waves); lane owns 4 columns = one
// uint of fp8 per edge. f32 accumulate, bf16 agg store.
// ---------------------------------------------------------------------------
__global__ __launch_bounds__(256) void k_gather(const int* __restrict__ rowstart,
                                                const int* __restrict__ srcs,
                                                const unsigned char* __restrict__ h8,
                                                unsigned short* __restrict__ aggbf)
{
    const int wid  = (blockIdx.x * 256 + threadIdx.x) >> 6;  // node id
    const int lane = threadIdx.x & 63;
    if (wid >= N_NODES) return;

    const int s0 = rowstart[wid];
    const int s1 = rowstart[wid + 1];

    float4 acc = make_float4(0.f, 0.f, 0.f, 0.f);
    const unsigned int* h32 = (const unsigned int*)h8;   // 64 uints per row

    int e = s0;
    for (; e + 3 < s1; e += 4) {
        unsigned int va = h32[(size_t)srcs[e]     * 64 + lane];
        unsigned int vb = h32[(size_t)srcs[e + 1] * 64 + lane];
        unsigned int vc = h32[(size_t)srcs[e + 2] * 64 + lane];
        unsigned int vd = h32[(size_t)srcs[e + 3] * 64 + lane];
        acc.x += (fp8tof(va & 0xffu)  + fp8tof(vb & 0xffu))  + (fp8tof(vc & 0xffu)  + fp8tof(vd & 0xffu));
        acc.y += (fp8tof((va >> 8) & 0xffu)  + fp8tof((vb >> 8) & 0xffu))  + (fp8tof((vc >> 8) & 0xffu)  + fp8tof((vd >> 8) & 0xffu));
        acc.z += (fp8tof((va >> 16) & 0xffu) + fp8tof((vb >> 16) & 0xffu)) + (fp8tof((vc >> 16) & 0xffu) + fp8tof((vd >> 16) & 0xffu));
        acc.w += (fp8tof(va >> 24)  + fp8tof(vb >> 24))  + (fp8tof(vc >> 24)  + fp8tof(vd >> 24));
    }
    for (; e < s1; ++e) {
        unsigned int va = h32[(size_t)srcs[e] * 64 + lane];
        acc.x += fp8tof(va & 0xffu);
        acc.y += fp8tof((va >> 8) & 0xffu);
        acc.z += fp8tof((va >> 16) & 0xffu);
        acc.w += fp8tof(va >> 24);
    }

    ushort4 o;
    o.x = f2bf(acc.x); o.y = f2bf(acc.y); o.z = f2bf(acc.z); o.w = f2bf(acc.w);
    ((ushort4*)aggbf)[(size_t)wid * 64 + lane] = o;
}

// ---------------------------------------------------------------------------
// MFMA msg layer: h2 = relu(agg @ msg_W.T + msg_b), column-summed into
// colsum without materializing h2.
// ---------------------------------------------------------------------------
__global__ __launch_bounds__(256) void k_msg_mfma(const unsigned short* __restrict__ aggbf,
                                                  const unsigned short* __restrict__ Wbf,
                                                  const float* __restrict__ b,
                                                  float* __restrict__ colsum)
{
    const int tid  = threadIdx.x;
    const int wave = tid >> 6;
    const int lane = tid & 63;
    const int lr   = lane & 15;
    const int lq   = lane >> 4;
    const int n0   = blockIdx.x * 64;
    const int colbase = wave * 64;

    f32x4 acc[4][4] = {};

#pragma unroll
    for (int kk = 0; kk < HID; kk += 32) {
        bf16x8 a[4], bb[4];
#pragma unroll
        for (int g = 0; g < 4; ++g)
            a[g] = *(const bf16x8*)(aggbf + (size_t)(n0 + g * 16 + lr) * HID + kk + lq * 8);
#pragma unroll
        for (int c = 0; c < 4; ++c)
            bb[c] = *(const bf16x8*)(Wbf + (size_t)(colbase + c * 16 + lr) * HID + kk + lq * 8);
#pragma unroll
        for (int g = 0; g < 4; ++g)
#pragma unroll
            for (int c = 0; c < 4; ++c)
                acc[g][c] = __builtin_amdgcn_mfma_f32_16x16x32_bf16(a[g], bb[c], acc[g][c], 0, 0, 0);
    }

#pragma unroll
    for (int c = 0; c < 4; ++c) {
        const int j = colbase + c * 16 + lr;
        const float bias = b[j];
        float part = 0.f;
#pragma unroll
        for (int g = 0; g < 4; ++g) {
            if (n0 + g * 16 < N_NODES) {      // 20000 % 16 == 0: exact cut
#pragma unroll
                for (int r = 0; r < 4; ++r) {
                    float v = acc[g][c][r] + bias;
                    part += v > 0.f ? v : 0.f;
                }
            }
        }
        part += __shfl_xor(part, 16);
        part += __shfl_xor(part, 32);
        if (lane < 16) unsafeAtomicAdd(&colsum[j], part);
    }
}

// ---------------------------------------------------------------------------
// Output matvecs from hmean = colsum / N.
// ---------------------------------------------------------------------------
__global__ __launch_bounds__(256) void k_out(const float* __restrict__ colsum,
                                             const float* __restrict__ W0,
                                             const float* __restrict__ b0,
                                             const float* __restrict__ W1,
                                             const float* __restrict__ b1,
                                             float* __restrict__ out)
{
    __shared__ float hm[HID];
    const int tid = threadIdx.x;
    hm[tid] = colsum[tid] * (1.0f / (float)N_NODES);
    __syncthreads();

    const int o = blockIdx.x * 256 + tid;
    const float* Wr;
    float bias;
    if (o < 8192) { Wr = W0 + (size_t)o * HID; bias = b0[o]; }
    else          { int o1 = o - 8192; Wr = W1 + (size_t)o1 * HID; bias = b1[o1]; }

    float s = bias;
    const float4* w4 = (const float4*)Wr;
    const float4* h4 = (const float4*)hm;
#pragma unroll 8
    for (int q = 0; q < 64; ++q) {
        float4 wv = w4[q];
        float4 hv = h4[q];
        s += wv.x * hv.x + wv.y * hv.y + wv.z * hv.z + wv.w * hv.w;
    }
    out[o] = s;
}

// ---------------------------------------------------------------------------
extern "C" void kernel_launch(void* const* d_in, const int* in_sizes, int n_in,
                              void* d_out, int out_size, void* d_ws, size_t ws_size,
                              hipStream_t stream)
{
    const float* x     = (const float*)d_in[0];
    const int*   ei    = (const int*)d_in[1];
    const float* emb_W = (const float*)d_in[2];
    const float* emb_b = (const float*)d_in[3];
    const float* msg_W = (const float*)d_in[4];
    const float* msg_b = (const float*)d_in[5];
    const float* W0    = (const float*)d_in[6];
    const float* b0    = (const float*)d_in[7];
    const float* W1    = (const float*)d_in[8];
    const float* b1    = (const float*)d_in[9];
    float* out = (float*)d_out;

    char* ws = (char*)d_ws;
    unsigned char*  h8    = (unsigned char*)(ws + WS_H_OFF);
    unsigned short* aggbf = (unsigned short*)(ws + WS_AGG_OFF);
    unsigned short* xbf   = (unsigned short*)(ws + WS_XBF_OFF);
    unsigned short* eWbf  = (unsigned short*)(ws + WS_EW_OFF);
    unsigned short* mWbf  = (unsigned short*)(ws + WS_MW_OFF);
    float* colsum = (float*)(ws + WS_CS_OFF);
    int* deg      = (int*)(ws + WS_DEG_OFF);
    int* rowstart = (int*)(ws + WS_ROW_OFF);
    int* srcs     = (int*)(ws + WS_SRC_OFF);

    // 1. convert to bf16 + zero colsum/deg
    k_convert<<<CONV_BLOCKS + ZERO_BLOCKS, 256, 0, stream>>>(
        x, emb_W, msg_W, xbf, eWbf, mWbf, (float4*)(ws + WS_CS_OFF));

    // 2. embed (MFMA, fp8 h out) + degree count
    k_embed_count<<<EMB_BLOCKS + CNT_BLOCKS, 256, 0, stream>>>(
        xbf, eWbf, emb_b, h8, ei, deg);

    // 3-4. CSR scan + fill
    k_scan<<<1, 1024, 0, stream>>>(deg, rowstart);
    k_fill<<<CNT_BLOCKS, 256, 0, stream>>>(ei, rowstart, deg, srcs);

    // 5. gather (one wave per node, fp8 h reads)
    k_gather<<<(N_NODES * 64 + 255) / 256, 256, 0, stream>>>(rowstart, srcs, h8, aggbf);

    // 6. msg layer + column-sum
    k_msg_mfma<<<EMB_BLOCKS, 256, 0, stream>>>(aggbf, mWbf, msg_b, colsum);

    // 7. output matvecs
    k_out<<<(8192 + 2048) / 256, 256, 0, stream>>>(colsum, W0, b0, W1, b1, out);
}

// Round 8
// 143.077 us; speedup vs baseline: 1.5535x; 1.2205x over previous
//
#include <hip/hip_runtime.h>
#include <hip/hip_bf16.h>

#define N_NODES 20000
#define N_EDGES 640000
#define HID 256
#define INDIM 128

// ---------- ws layout (bytes) ----------
#define WS_H_OFF    0u          // h fp8: 20000*256 = 5,120,000
#define WS_AGG_OFF  5120000u    // agg bf16: 20000*256*2 = 10,240,000
#define WS_XBF_OFF  15360000u   // x bf16: 20000*128*2 = 5,120,000
#define WS_EW_OFF   20480000u   // emb_W bf16: 65,536
#define WS_MW_OFF   20545536u   // msg_W bf16: 131,072
#define WS_CS_OFF   20676608u   // colsum f32: 1024   (zeroed; contiguous with deg)
#define WS_DEG_OFF  20677632u   // deg: 80,000        (zeroed; doubles as fill cursor)
#define WS_ROW_OFF  20757632u   // rowstart: 80,004 (+124 pad)
#define WS_SRC_OFF  20837760u   // srcs: 2,560,000
#define WS_NEEDED   23397760u

#define X_ELEMS  (N_NODES * INDIM)          // 2,560,000
#define EW_ELEMS (HID * INDIM)              // 32,768
#define MW_ELEMS (HID * HID)                // 65,536
#define CONV_BLOCKS ((X_ELEMS + EW_ELEMS + MW_ELEMS) / 8 / 256)   // 1298 exact
#define ZERO_BYTES  (1024 + 80000)          // colsum + deg, contiguous
#define ZERO_F4     (ZERO_BYTES / 16)       // 5064 exact
#define ZERO_BLOCKS ((ZERO_F4 + 255) / 256) // 20

#define EMB_BLOCKS  ((N_NODES + 63) / 64)   // 313
#define CNT_BLOCKS  (N_EDGES / 256)         // 2500 exact

typedef __attribute__((ext_vector_type(8))) short bf16x8;
typedef __attribute__((ext_vector_type(4))) float f32x4;
typedef __attribute__((ext_vector_type(2))) float f32x2;

__device__ inline unsigned short f2bf(float v) {
    union { float f; unsigned int u; } c; c.f = v;
    unsigned int lsb = (c.u >> 16) & 1u;
    c.u += 0x7fffu + lsb;                 // round-to-nearest-even
    return (unsigned short)(c.u >> 16);
}
__device__ inline float bf2f(unsigned short u) {
    union { float f; unsigned int u; } c; c.u = ((unsigned int)u) << 16;
    return c.f;
}

// ---- fp8 e4m3fn (OCP), nonnegative inputs only (h is post-relu) ----------
// encode: RTNE, exact for 0 and denormals; h <= ~4 so no sat needed.
// decode on the gather side uses HW v_cvt_pk_f32_fp8 (OCP on gfx950).
__device__ inline unsigned char f2fp8(float v) {
    union { float f; unsigned int u; } c; c.f = v;
    if (v == 0.f) return 0;
    int e = (int)((c.u >> 23) & 0xff) - 127;
    if (e >= -6) {
        unsigned int mant = c.u & 0x7fffffu;
        unsigned int base = ((unsigned int)(e + 7) << 3) | (mant >> 20);
        unsigned int rem  = mant & 0xfffffu;
        base += (rem > 0x80000u) || (rem == 0x80000u && (base & 1u));
        return (unsigned char)base;
    } else {
        // denormal: m = round(v * 512), m in [0,8] (m==8 -> 0x08, exact)
        return (unsigned char)__builtin_rintf(v * 512.0f);
    }
}

// ---------------------------------------------------------------------------
// Convert x, emb_W, msg_W to bf16; tail blocks zero colsum+deg (81 KB).
// ---------------------------------------------------------------------------
__global__ __launch_bounds__(256) void k_convert(const float* __restrict__ x,
                                                 const float* __restrict__ eW,
                                                 const float* __restrict__ mW,
                                                 unsigned short* __restrict__ xbf,
                                                 unsigned short* __restrict__ eWbf,
                                                 unsigned short* __restrict__ mWbf,
                                                 float4* __restrict__ zbase)
{
    if (blockIdx.x >= CONV_BLOCKS) {
        const int zi = (blockIdx.x - CONV_BLOCKS) * 256 + threadIdx.x;
        if (zi < ZERO_F4) zbase[zi] = make_float4(0.f, 0.f, 0.f, 0.f);
        return;
    }
    const int t = blockIdx.x * 256 + threadIdx.x;
    const int i8 = t * 8;
    const float* src;
    unsigned short* dst;
    int off;
    if (i8 < X_ELEMS)                 { src = x;  dst = xbf;  off = i8; }
    else if (i8 < X_ELEMS + EW_ELEMS) { src = eW; dst = eWbf; off = i8 - X_ELEMS; }
    else                              { src = mW; dst = mWbf; off = i8 - X_ELEMS - EW_ELEMS; }

    float4 a = *(const float4*)(src + off);
    float4 b = *(const float4*)(src + off + 4);
    unsigned short o[8] = { f2bf(a.x), f2bf(a.y), f2bf(a.z), f2bf(a.w),
                            f2bf(b.x), f2bf(b.y), f2bf(b.z), f2bf(b.w) };
    *(bf16x8*)(dst + off) = *(bf16x8*)o;
}

// ---------------------------------------------------------------------------
// MFMA embed (blocks < EMB_BLOCKS) + edge-degree count (blocks >= EMB_BLOCKS).
// h stored as fp8 e4m3 (5.1 MB -> mostly per-XCD-L2-resident for gather).
// ---------------------------------------------------------------------------
__global__ __launch_bounds__(256) void k_embed_count(const unsigned short* __restrict__ xbf,
                                                     const unsigned short* __restrict__ Wbf,
                                                     const float* __restrict__ b,
                                                     unsigned char* __restrict__ h8,
                                                     const int* __restrict__ ei,
                                                     int* __restrict__ deg)
{
    if (blockIdx.x >= EMB_BLOCKS) {
        const int e = (blockIdx.x - EMB_BLOCKS) * 256 + threadIdx.x;
        if (e < N_EDGES) atomicAdd(&deg[ei[e]], 1);
        return;
    }

    const int tid  = threadIdx.x;
    const int wave = tid >> 6;
    const int lane = tid & 63;
    const int lr   = lane & 15;
    const int lq   = lane >> 4;
    const int n0   = blockIdx.x * 64;
    const int colbase = wave * 64;

    f32x4 acc[4][4] = {};

#pragma unroll
    for (int kk = 0; kk < INDIM; kk += 32) {
        bf16x8 a[4], bb[4];
#pragma unroll
        for (int g = 0; g < 4; ++g)
            a[g] = *(const bf16x8*)(xbf + (size_t)(n0 + g * 16 + lr) * INDIM + kk + lq * 8);
#pragma unroll
        for (int c = 0; c < 4; ++c)
            bb[c] = *(const bf16x8*)(Wbf + (size_t)(colbase + c * 16 + lr) * INDIM + kk + lq * 8);
#pragma unroll
        for (int g = 0; g < 4; ++g)
#pragma unroll
            for (int c = 0; c < 4; ++c)
                acc[g][c] = __builtin_amdgcn_mfma_f32_16x16x32_bf16(a[g], bb[c], acc[g][c], 0, 0, 0);
    }

#pragma unroll
    for (int c = 0; c < 4; ++c) {
        const int j = colbase + c * 16 + lr;
        const float bias = b[j];
#pragma unroll
        for (int g = 0; g < 4; ++g) {
            const int nbase = n0 + g * 16 + lq * 4;
#pragma unroll
            for (int r = 0; r < 4; ++r) {
                const int n = nbase + r;
                if (n < N_NODES) {
                    float v = acc[g][c][r] + bias;
                    v = v > 0.f ? v : 0.f;
                    h8[(size_t)n * HID + j] = f2fp8(v);
                }
            }
        }
    }
}

// ---------------------------------------------------------------------------
// Exclusive prefix sum of deg -> rowstart (single block).
// ---------------------------------------------------------------------------
__global__ __launch_bounds__(1024) void k_scan(const int* __restrict__ deg,
                                               int* __restrict__ rowstart)
{
    __shared__ int sums[1024];
    const int t = threadIdx.x;
    const int per = 20;                     // 1024*20 = 20480 >= 20000
    const int base = t * per;

    int local[per];
    int s = 0;
#pragma unroll
    for (int i = 0; i < per; ++i) {
        int idx = base + i;
        int v = (idx < N_NODES) ? deg[idx] : 0;
        local[i] = s;
        s += v;
    }
    sums[t] = s;
    __syncthreads();

    for (int off = 1; off < 1024; off <<= 1) {
        int v = 0;
        if (t >= off) v = sums[t - off];
        __syncthreads();
        if (t >= off) sums[t] += v;
        __syncthreads();
    }

    const int pre = (t == 0) ? 0 : sums[t - 1];
#pragma unroll
    for (int i = 0; i < per; ++i) {
        int idx = base + i;
        if (idx < N_NODES) rowstart[idx] = pre + local[i];
    }
    if (t == 1023) rowstart[N_NODES] = sums[1023];
}

// deg[dst] still holds the count; consume it as a countdown cursor.
__global__ __launch_bounds__(256) void k_fill(const int* __restrict__ ei,
                                              const int* __restrict__ rowstart,
                                              int* __restrict__ deg,
                                              int* __restrict__ srcs)
{
    const int e = blockIdx.x * 256 + threadIdx.x;
    if (e >= N_EDGES) return;
    const int dst = ei[e];
    const int src = ei[N_EDGES + e];
    const int pos = rowstart[dst] + atomicSub(&deg[dst], 1) - 1;
    srcs[pos] = src;
}

// ---------------------------------------------------------------------------
// Gather: one wave per dst node (20000 waves); lane owns 4 columns = one
// uint of fp8 per edge. HW fp8->f32 decode (v_cvt_pk_f32_fp8, OCP on
// gfx950): 2 instrs per 4 values. 8-deep edge unroll for latency hiding.
// ---------------------------------------------------------------------------
__global__ __launch_bounds__(256) void k_gather(const int* __restrict__ rowstart,
                                                const int* __restrict__ srcs,
                                                const unsigned char* __restrict__ h8,
                                                unsigned short* __restrict__ aggbf)
{
    const int wid  = (blockIdx.x * 256 + threadIdx.x) >> 6;  // node id
    const int lane = threadIdx.x & 63;
    if (wid >= N_NODES) return;

    const int s0 = rowstart[wid];
    const int s1 = rowstart[wid + 1];

    float4 acc = make_float4(0.f, 0.f, 0.f, 0.f);
    const unsigned int* h32 = (const unsigned int*)h8;   // 64 uints per row

    int e = s0;
    for (; e + 7 < s1; e += 8) {
        int s[8];
#pragma unroll
        for (int k = 0; k < 8; ++k) s[k] = srcs[e + k];
        unsigned int v[8];
#pragma unroll
        for (int k = 0; k < 8; ++k) v[k] = h32[(size_t)s[k] * 64 + lane];
#pragma unroll
        for (int k = 0; k < 8; ++k) {
            f32x2 lo = __builtin_amdgcn_cvt_pk_f32_fp8(v[k], false);
            f32x2 hi = __builtin_amdgcn_cvt_pk_f32_fp8(v[k], true);
            acc.x += lo[0]; acc.y += lo[1]; acc.z += hi[0]; acc.w += hi[1];
        }
    }
    for (; e < s1; ++e) {
        unsigned int va = h32[(size_t)srcs[e] * 64 + lane];
        f32x2 lo = __builtin_amdgcn_cvt_pk_f32_fp8(va, false);
        f32x2 hi = __builtin_amdgcn_cvt_pk_f32_fp8(va, true);
        acc.x += lo[0]; acc.y += lo[1]; acc.z += hi[0]; acc.w += hi[1];
    }

    ushort4 o;
    o.x = f2bf(acc.x); o.y = f2bf(acc.y); o.z = f2bf(acc.z); o.w = f2bf(acc.w);
    ((ushort4*)aggbf)[(size_t)wid * 64 + lane] = o;
}

// ---------------------------------------------------------------------------
// MFMA msg layer: h2 = relu(agg @ msg_W.T + msg_b), column-summed into
// colsum without materializing h2.
// ---------------------------------------------------------------------------
__global__ __launch_bounds__(256) void k_msg_mfma(const unsigned short* __restrict__ aggbf,
                                                  const unsigned short* __restrict__ Wbf,
                                                  const float* __restrict__ b,
                                                  float* __restrict__ colsum)
{
    const int tid  = threadIdx.x;
    const int wave = tid >> 6;
    const int lane = tid & 63;
    const int lr   = lane & 15;
    const int lq   = lane >> 4;
    const int n0   = blockIdx.x * 64;
    const int colbase = wave * 64;

    f32x4 acc[4][4] = {};

#pragma unroll
    for (int kk = 0; kk < HID; kk += 32) {
        bf16x8 a[4], bb[4];
#pragma unroll
        for (int g = 0; g < 4; ++g)
            a[g] = *(const bf16x8*)(aggbf + (size_t)(n0 + g * 16 + lr) * HID + kk + lq * 8);
#pragma unroll
        for (int c = 0; c < 4; ++c)
            bb[c] = *(const bf16x8*)(Wbf + (size_t)(colbase + c * 16 + lr) * HID + kk + lq * 8);
#pragma unroll
        for (int g = 0; g < 4; ++g)
#pragma unroll
            for (int c = 0; c < 4; ++c)
                acc[g][c] = __builtin_amdgcn_mfma_f32_16x16x32_bf16(a[g], bb[c], acc[g][c], 0, 0, 0);
    }

#pragma unroll
    for (int c = 0; c < 4; ++c) {
        const int j = colbase + c * 16 + lr;
        const float bias = b[j];
        float part = 0.f;
#pragma unroll
        for (int g = 0; g < 4; ++g) {
            if (n0 + g * 16 < N_NODES) {      // 20000 % 16 == 0: exact cut
#pragma unroll
                for (int r = 0; r < 4; ++r) {
                    float v = acc[g][c][r] + bias;
                    part += v > 0.f ? v : 0.f;
                }
            }
        }
        part += __shfl_xor(part, 16);
        part += __shfl_xor(part, 32);
        if (lane < 16) unsafeAtomicAdd(&colsum[j], part);
    }
}

// ---------------------------------------------------------------------------
// Output matvecs from hmean = colsum / N.
// ---------------------------------------------------------------------------
__global__ __launch_bounds__(256) void k_out(const float* __restrict__ colsum,
                                             const float* __restrict__ W0,
                                             const float* __restrict__ b0,
                                             const float* __restrict__ W1,
                                             const float* __restrict__ b1,
                                             float* __restrict__ out)
{
    __shared__ float hm[HID];
    const int tid = threadIdx.x;
    hm[tid] = colsum[tid] * (1.0f / (float)N_NODES);
    __syncthreads();

    const int o = blockIdx.x * 256 + tid;
    const float* Wr;
    float bias;
    if (o < 8192) { Wr = W0 + (size_t)o * HID; bias = b0[o]; }
    else          { int o1 = o - 8192; Wr = W1 + (size_t)o1 * HID; bias = b1[o1]; }

    float s = bias;
    const float4* w4 = (const float4*)Wr;
    const float4* h4 = (const float4*)hm;
#pragma unroll 8
    for (int q = 0; q < 64; ++q) {
        float4 wv = w4[q];
        float4 hv = h4[q];
        s += wv.x * hv.x + wv.y * hv.y + wv.z * hv.z + wv.w * hv.w;
    }
    out[o] = s;
}

// ---------------------------------------------------------------------------
extern "C" void kernel_launch(void* const* d_in, const int* in_sizes, int n_in,
                              void* d_out, int out_size, void* d_ws, size_t ws_size,
                              hipStream_t stream)
{
    const float* x     = (const float*)d_in[0];
    const int*   ei    = (const int*)d_in[1];
    const float* emb_W = (const float*)d_in[2];
    const float* emb_b = (const float*)d_in[3];
    const float* msg_W = (const float*)d_in[4];
    const float* msg_b = (const float*)d_in[5];
    const float* W0    = (const float*)d_in[6];
    const float* b0    = (const float*)d_in[7];
    const float* W1    = (const float*)d_in[8];
    const float* b1    = (const float*)d_in[9];
    float* out = (float*)d_out;

    char* ws = (char*)d_ws;
    unsigned char*  h8    = (unsigned char*)(ws + WS_H_OFF);
    unsigned short* aggbf = (unsigned short*)(ws + WS_AGG_OFF);
    unsigned short* xbf   = (unsigned short*)(ws + WS_XBF_OFF);
    unsigned short* eWbf  = (unsigned short*)(ws + WS_EW_OFF);
    unsigned short* mWbf  = (unsigned short*)(ws + WS_MW_OFF);
    float* colsum = (float*)(ws + WS_CS_OFF);
    int* deg      = (int*)(ws + WS_DEG_OFF);
    int* rowstart = (int*)(ws + WS_ROW_OFF);
    int* srcs     = (int*)(ws + WS_SRC_OFF);

    // 1. convert to bf16 + zero colsum/deg
    k_convert<<<CONV_BLOCKS + ZERO_BLOCKS, 256, 0, stream>>>(
        x, emb_W, msg_W, xbf, eWbf, mWbf, (float4*)(ws + WS_CS_OFF));

    // 2. embed (MFMA, fp8 h out) + degree count
    k_embed_count<<<EMB_BLOCKS + CNT_BLOCKS, 256, 0, stream>>>(
        xbf, eWbf, emb_b, h8, ei, deg);

    // 3-4. CSR scan + fill
    k_scan<<<1, 1024, 0, stream>>>(deg, rowstart);
    k_fill<<<CNT_BLOCKS, 256, 0, stream>>>(ei, rowstart, deg, srcs);

    // 5. gather (one wave per node, HW fp8 decode)
    k_gather<<<(N_NODES * 64 + 255) / 256, 256, 0, stream>>>(rowstart, srcs, h8, aggbf);

    // 6. msg layer + column-sum
    k_msg_mfma<<<EMB_BLOCKS, 256, 0, stream>>>(aggbf, mWbf, msg_b, colsum);

    // 7. output matvecs
    k_out<<<(8192 + 2048) / 256, 256, 0, stream>>>(colsum, W0, b0, W1, b1, out);
}